// Round 1
// baseline (310525.903 us; speedup 1.0000x reference)
//
#include <hip/hip_runtime.h>
#include <cstdint>
#include <cstddef>

#define H        2048
#define T_STEPS  16384
#define G        256     // workgroups == CUs, 1 WG/CU (LDS-limited)
#define HC       8       // h indices per WG (H/G)
#define NROW     24      // 3 gates * HC rows of w_hh per WG
#define WGSIZE   256
#define CHUNKS   256     // 2048 cols / 8 per chunk

// LDS layout (bytes)
#define LDS_W_OFF    0                      // bf16 weights: 24 rows * 2048 cols * 2B
#define LDS_H_OFF    98304                  // float h_s[2048]
#define LDS_GC_OFF   (98304 + 8192)         // float4 gc[24]: (wi0, wi1, b_ih, b_hh)
#define LDS_RED_OFF  (98304 + 8192 + 384)   // float red[8]
#define LDS_BYTES    (98304 + 8192 + 384 + 32)

__device__ __forceinline__ float sigmoidf_(float x) {
    return 1.0f / (1.0f + __expf(-x));
}
__device__ __forceinline__ float tanhf_(float x) {
    return 1.0f - 2.0f / (__expf(2.0f * x) + 1.0f);
}
// fp32 -> bf16 round-to-nearest-even (inputs are finite gaussians; no NaN care)
__device__ __forceinline__ uint16_t f2bf(float f) {
    uint32_t u = __builtin_bit_cast(uint32_t, f);
    return (uint16_t)((u + 0x7FFFu + ((u >> 16) & 1u)) >> 16);
}
__device__ __forceinline__ float bflo(uint32_t d) { return __builtin_bit_cast(float, d << 16); }
__device__ __forceinline__ float bfhi(uint32_t d) { return __builtin_bit_cast(float, d & 0xFFFF0000u); }

__global__ void init_stamps_kernel(int* __restrict__ stamps) {
    if (threadIdx.x < G) stamps[threadIdx.x] = -1;
}

extern "C" __global__ void __launch_bounds__(WGSIZE, 1)
gru_persistent_kernel(const float* __restrict__ samples,
                      const float* __restrict__ w_ih,
                      const float* __restrict__ w_hh,
                      const float* __restrict__ b_ih,
                      const float* __restrict__ b_hh,
                      const float* __restrict__ fc_w,
                      const float* __restrict__ fc_b,
                      float* __restrict__ out,
                      float* __restrict__ hbuf,    // [2][H] in d_ws
                      int*   __restrict__ stamps)  // [G]   in d_ws
{
    extern __shared__ char smem[];
    uint16_t* wlds = (uint16_t*)(smem + LDS_W_OFF);
    float*    h_s  = (float*)(smem + LDS_H_OFF);
    float4*   gc   = (float4*)(smem + LDS_GC_OFF);
    float*    red  = (float*)(smem + LDS_RED_OFF);

    const int g    = blockIdx.x;
    const int tid  = threadIdx.x;
    const int wave = tid >> 6;
    const int lane = tid & 63;

    // ---- one-time: stage this WG's 24 w_hh rows into LDS as bf16 ----
    // Row slot rho = wave_r*6 + gate*2 + jj ; global h index i = g*8 + 2*wave_r + jj
    // Chunk-interleaved within a row: chunk c (8 bf16, 16B) at byte off rho*4096 + c*16.
    for (int rho = 0; rho < NROW; ++rho) {
        int w_r  = rho / 6;
        int rem  = rho - 6 * w_r;
        int gate = rem >> 1;
        int jj   = rem & 1;
        int grow = gate * H + g * HC + 2 * w_r + jj;
        const float* src = w_hh + (size_t)grow * H + tid * 8;
        float4 a = *(const float4*)(src);
        float4 b = *(const float4*)(src + 4);
        uint4 p;
        p.x = (uint32_t)f2bf(a.x) | ((uint32_t)f2bf(a.y) << 16);
        p.y = (uint32_t)f2bf(a.z) | ((uint32_t)f2bf(a.w) << 16);
        p.z = (uint32_t)f2bf(b.x) | ((uint32_t)f2bf(b.y) << 16);
        p.w = (uint32_t)f2bf(b.z) | ((uint32_t)f2bf(b.w) << 16);
        *(uint4*)(wlds + rho * 2048 + tid * 8) = p;
    }
    if (tid < NROW) {
        int rho  = tid;
        int w_r  = rho / 6;
        int rem  = rho - 6 * w_r;
        int gate = rem >> 1;
        int jj   = rem & 1;
        int grow = gate * H + g * HC + 2 * w_r + jj;
        gc[rho] = make_float4(w_ih[grow * 2 + 0], w_ih[grow * 2 + 1], b_ih[grow], b_hh[grow]);
    }
    // h[0] = 0 for our 8 indices (parity-0 buffer)
    if (tid < HC) {
        __hip_atomic_store(hbuf + g * HC + tid, 0.0f,
                           __ATOMIC_RELAXED, __HIP_MEMORY_SCOPE_AGENT);
    }
    __syncthreads();   // compiler drains vmcnt before s_barrier
    if (tid == 0) {
        __hip_atomic_store(&stamps[g], 0, __ATOMIC_RELEASE, __HIP_MEMORY_SCOPE_AGENT);
    }

    // ---- 16384 sequential steps ----
    for (int t = 0; t < T_STEPS; ++t) {
        // read-only data: safe to load any time; overlaps the stamp spin
        float2 sv = *(const float2*)(samples + 2 * (size_t)t);

        // wait until every WG has published its chunk of h[t]
        if (__hip_atomic_load(&stamps[tid], __ATOMIC_RELAXED, __HIP_MEMORY_SCOPE_AGENT) < t) {
            do { __builtin_amdgcn_s_sleep(1); }
            while (__hip_atomic_load(&stamps[tid], __ATOMIC_RELAXED, __HIP_MEMORY_SCOPE_AGENT) < t);
        }
        __syncthreads();
        __builtin_amdgcn_fence(__ATOMIC_ACQUIRE, "agent");  // invalidate L1/L2 before h reads

        // stage h[t] (parity t&1) global -> LDS, 8 floats/thread, coalesced
        const float* hsrc = hbuf + (size_t)(t & 1) * H;
        float4 v0 = *(const float4*)(hsrc + tid * 8);
        float4 v1 = *(const float4*)(hsrc + tid * 8 + 4);
        *(float4*)(h_s + tid * 8)     = v0;
        *(float4*)(h_s + tid * 8 + 4) = v1;
        __syncthreads();

        // lane l consumes chunks {l, l+64, l+128, l+192}: LDS reads are lane-sequential
        float hv[4][8];
#pragma unroll
        for (int k = 0; k < 4; ++k) {
            const float4* hp = (const float4*)(h_s + (lane + 64 * k) * 8);
            float4 a = hp[0], b = hp[1];
            hv[k][0] = a.x; hv[k][1] = a.y; hv[k][2] = a.z; hv[k][3] = a.w;
            hv[k][4] = b.x; hv[k][5] = b.y; hv[k][6] = b.z; hv[k][7] = b.w;
        }
        float acc[6];
#pragma unroll
        for (int q = 0; q < 6; ++q) {
            const uint16_t* wrow = wlds + (wave * 6 + q) * 2048;
            float s = 0.0f;
#pragma unroll
            for (int k = 0; k < 4; ++k) {
                uint4 wv = *(const uint4*)(wrow + (lane + 64 * k) * 8);
                s += bflo(wv.x) * hv[k][0] + bfhi(wv.x) * hv[k][1]
                   + bflo(wv.y) * hv[k][2] + bfhi(wv.y) * hv[k][3]
                   + bflo(wv.z) * hv[k][4] + bfhi(wv.z) * hv[k][5]
                   + bflo(wv.w) * hv[k][6] + bfhi(wv.w) * hv[k][7];
            }
            acc[q] = s;
        }
        // full-wave butterfly: every lane ends with the row sums
#pragma unroll
        for (int off = 32; off > 0; off >>= 1) {
#pragma unroll
            for (int q = 0; q < 6; ++q)
                acc[q] += __shfl_xor(acc[q], off, 64);
        }

        if (lane == 0) {
#pragma unroll
            for (int jj = 0; jj < 2; ++jj) {
                int rr = wave * 6 + jj;         // r-gate row slot
                int rz = wave * 6 + 2 + jj;     // z-gate
                int rn = wave * 6 + 4 + jj;     // n-gate
                float4 cr = gc[rr], cz = gc[rz], cn = gc[rn];
                float xr = sv.x * cr.x + sv.y * cr.y + cr.z;
                float xz = sv.x * cz.x + sv.y * cz.y + cz.z;
                float xn = sv.x * cn.x + sv.y * cn.y + cn.z;
                float hr = acc[jj]     + cr.w;
                float hz = acc[2 + jj] + cz.w;
                float hn = acc[4 + jj] + cn.w;
                float r = sigmoidf_(xr + hr);
                float z = sigmoidf_(xz + hz);
                float n = tanhf_(xn + r * hn);
                int i = g * HC + 2 * wave + jj;
                float hold = h_s[i];
                float hnew = (1.0f - z) * n + z * hold;
                __hip_atomic_store(hbuf + (size_t)((t + 1) & 1) * H + i, hnew,
                                   __ATOMIC_RELAXED, __HIP_MEMORY_SCOPE_AGENT);
            }
        }
        __syncthreads();   // drains the h stores (vmcnt) before the stamp release
        if (tid == 0) {
            __hip_atomic_store(&stamps[g], t + 1, __ATOMIC_RELEASE, __HIP_MEMORY_SCOPE_AGENT);
        }
    }

    // ---- epilogue: WG 0 computes sigmoid(h_T . fc_w + fc_b) ----
    if (g == 0) {
        while (__hip_atomic_load(&stamps[tid], __ATOMIC_RELAXED, __HIP_MEMORY_SCOPE_AGENT) < T_STEPS) {
            __builtin_amdgcn_s_sleep(1);
        }
        __syncthreads();
        __builtin_amdgcn_fence(__ATOMIC_ACQUIRE, "agent");
        const float* hT = hbuf + (size_t)(T_STEPS & 1) * H;   // parity 0
        float p = 0.0f;
#pragma unroll
        for (int e = 0; e < 8; ++e)
            p += hT[tid * 8 + e] * fc_w[tid * 8 + e];
#pragma unroll
        for (int off = 32; off > 0; off >>= 1)
            p += __shfl_xor(p, off, 64);
        if (lane == 0) red[wave] = p;
        __syncthreads();
        if (tid == 0) {
            float s = red[0] + red[1] + red[2] + red[3];
            out[0] = sigmoidf_(s + fc_b[0]);
        }
    }
}

extern "C" void kernel_launch(void* const* d_in, const int* in_sizes, int n_in,
                              void* d_out, int out_size, void* d_ws, size_t ws_size,
                              hipStream_t stream) {
    const float* samples = (const float*)d_in[0];
    const float* w_ih    = (const float*)d_in[1];
    const float* w_hh    = (const float*)d_in[2];
    const float* b_ih    = (const float*)d_in[3];
    const float* b_hh    = (const float*)d_in[4];
    const float* fc_w    = (const float*)d_in[5];
    const float* fc_b    = (const float*)d_in[6];
    float* out    = (float*)d_out;
    float* hbuf   = (float*)d_ws;                                   // 16 KB
    int*   stamps = (int*)((char*)d_ws + 2 * H * sizeof(float));    // 1 KB

    // workspace is poisoned before every launch: make stamps sane first
    hipLaunchKernelGGL(init_stamps_kernel, dim3(1), dim3(WGSIZE), 0, stream, stamps);

    hipFuncSetAttribute((const void*)gru_persistent_kernel,
                        hipFuncAttributeMaxDynamicSharedMemorySize, LDS_BYTES);

    void* args[] = {(void*)&samples, (void*)&w_ih, (void*)&w_hh, (void*)&b_ih,
                    (void*)&b_hh, (void*)&fc_w, (void*)&fc_b,
                    (void*)&out, (void*)&hbuf, (void*)&stamps};
    hipError_t rc = hipLaunchCooperativeKernel(
        reinterpret_cast<void*>(gru_persistent_kernel),
        dim3(G), dim3(WGSIZE), args, LDS_BYTES, stream);
    if (rc != hipSuccess) {
        // fallback: plain launch — 256 blocks of 1-WG/CU still co-schedule on an idle chip
        hipLaunchKernelGGL(gru_persistent_kernel, dim3(G), dim3(WGSIZE), LDS_BYTES, stream,
                           samples, w_ih, w_hh, b_ih, b_hh, fc_w, fc_b, out, hbuf, stamps);
    }
}

// Round 2
// 139043.066 us; speedup vs baseline: 2.2333x; 2.2333x over previous
//
#include <hip/hip_runtime.h>
#include <cstdint>
#include <cstddef>

#define H        2048
#define T_STEPS  16384
#define G        256     // workgroups == CUs, 1 WG/CU (LDS-limited)
#define HC       8       // h indices per WG (H/G)
#define NROW     24      // 3 gates * HC rows of w_hh per WG
#define WGSIZE   256

// LDS layout (bytes)
#define LDS_W_OFF    0                      // bf16 weights: 24 rows * 2048 cols * 2B
#define LDS_H_OFF    98304                  // float h_s[2048]
#define LDS_GC_OFF   (98304 + 8192)         // float4 gc[24]: (wi0, wi1, b_ih, b_hh)
#define LDS_RED_OFF  (98304 + 8192 + 384)   // float red[8]
#define LDS_BYTES    (98304 + 8192 + 384 + 32)

typedef unsigned long long ull;

__device__ __forceinline__ float sigmoidf_(float x) {
    return 1.0f / (1.0f + __expf(-x));
}
__device__ __forceinline__ float tanhf_(float x) {
    return 1.0f - 2.0f / (__expf(2.0f * x) + 1.0f);
}
// fp32 -> bf16 round-to-nearest-even
__device__ __forceinline__ uint16_t f2bf(float f) {
    uint32_t u = __builtin_bit_cast(uint32_t, f);
    return (uint16_t)((u + 0x7FFFu + ((u >> 16) & 1u)) >> 16);
}
__device__ __forceinline__ float bflo(uint32_t d) { return __builtin_bit_cast(float, d << 16); }
__device__ __forceinline__ float bfhi(uint32_t d) { return __builtin_bit_cast(float, d & 0xFFFF0000u); }

// relaxed agent-scope atomics: bypass non-coherent L2, NO fence instructions
__device__ __forceinline__ ull ld_agent_u64(const ull* p) {
    return __hip_atomic_load(p, __ATOMIC_RELAXED, __HIP_MEMORY_SCOPE_AGENT);
}
__device__ __forceinline__ void st_agent_u64(ull* p, ull v) {
    __hip_atomic_store(p, v, __ATOMIC_RELAXED, __HIP_MEMORY_SCOPE_AGENT);
}
__device__ __forceinline__ int ld_agent_i32(const int* p) {
    return __hip_atomic_load(p, __ATOMIC_RELAXED, __HIP_MEMORY_SCOPE_AGENT);
}
__device__ __forceinline__ void st_agent_i32(int* p, int v) {
    __hip_atomic_store(p, v, __ATOMIC_RELAXED, __HIP_MEMORY_SCOPE_AGENT);
}
// wait until this wave's outstanding vector-memory stores are committed
__device__ __forceinline__ void wait_vm0() {
    asm volatile("s_waitcnt vmcnt(0)" ::: "memory");
}

__global__ void init_stamps_kernel(int* __restrict__ stamps) {
    if (threadIdx.x < G) stamps[threadIdx.x] = -1;
}

extern "C" __global__ void __launch_bounds__(WGSIZE, 1)
gru_persistent_kernel(const float* __restrict__ samples,
                      const float* __restrict__ w_ih,
                      const float* __restrict__ w_hh,
                      const float* __restrict__ b_ih,
                      const float* __restrict__ b_hh,
                      const float* __restrict__ fc_w,
                      const float* __restrict__ fc_b,
                      float* __restrict__ out,
                      float* __restrict__ hbuf,    // [2][H] in d_ws
                      int*   __restrict__ stamps)  // [G]   in d_ws
{
    extern __shared__ char smem[];
    uint16_t* wlds = (uint16_t*)(smem + LDS_W_OFF);
    float*    h_s  = (float*)(smem + LDS_H_OFF);
    float4*   gc   = (float4*)(smem + LDS_GC_OFF);
    float*    red  = (float*)(smem + LDS_RED_OFF);

    const int g    = blockIdx.x;
    const int tid  = threadIdx.x;
    const int wave = tid >> 6;
    const int lane = tid & 63;

    // ---- one-time: stage this WG's 24 w_hh rows into LDS as bf16 ----
    // Row slot rho = wave_r*6 + gate*2 + jj ; global h index i = g*8 + 2*wave_r + jj
    for (int rho = 0; rho < NROW; ++rho) {
        int w_r  = rho / 6;
        int rem  = rho - 6 * w_r;
        int gate = rem >> 1;
        int jj   = rem & 1;
        int grow = gate * H + g * HC + 2 * w_r + jj;
        const float* src = w_hh + (size_t)grow * H + tid * 8;
        float4 a = *(const float4*)(src);
        float4 b = *(const float4*)(src + 4);
        uint4 p;
        p.x = (uint32_t)f2bf(a.x) | ((uint32_t)f2bf(a.y) << 16);
        p.y = (uint32_t)f2bf(a.z) | ((uint32_t)f2bf(a.w) << 16);
        p.z = (uint32_t)f2bf(b.x) | ((uint32_t)f2bf(b.y) << 16);
        p.w = (uint32_t)f2bf(b.z) | ((uint32_t)f2bf(b.w) << 16);
        *(uint4*)(wlds + rho * 2048 + tid * 8) = p;
    }
    if (tid < NROW) {
        int rho  = tid;
        int w_r  = rho / 6;
        int rem  = rho - 6 * w_r;
        int gate = rem >> 1;
        int jj   = rem & 1;
        int grow = gate * H + g * HC + 2 * w_r + jj;
        gc[rho] = make_float4(w_ih[grow * 2 + 0], w_ih[grow * 2 + 1], b_ih[grow], b_hh[grow]);
    }
    // h[0] = 0 for our 8 indices (parity-0 buffer): one 8B store per pair
    if (tid < HC / 2) {
        st_agent_u64((ull*)(hbuf + g * HC) + tid, 0ull);
    }
    wait_vm0();
    __syncthreads();
    if (tid == 0) st_agent_i32(&stamps[g], 0);

    // ---- 16384 sequential steps ----
    for (int t = 0; t < T_STEPS; ++t) {
        float2 sv = *(const float2*)(samples + 2 * (size_t)t);

        // thread tid waits for WG tid's chunk of h[t], then loads exactly that
        // 32B slice (stamp and data are 1:1 — no extra fence needed)
        if (ld_agent_i32(&stamps[tid]) < t) {
            do { __builtin_amdgcn_s_sleep(1); }
            while (ld_agent_i32(&stamps[tid]) < t);
        }
        __atomic_signal_fence(__ATOMIC_SEQ_CST);  // compiler-only barrier

        const ull* hsrc = (const ull*)(hbuf + (size_t)(t & 1) * H) + tid * 4;
        ull d0 = ld_agent_u64(hsrc + 0);
        ull d1 = ld_agent_u64(hsrc + 1);
        ull d2 = ld_agent_u64(hsrc + 2);
        ull d3 = ld_agent_u64(hsrc + 3);
        ull* hdst = (ull*)(h_s + tid * 8);
        hdst[0] = d0; hdst[1] = d1; hdst[2] = d2; hdst[3] = d3;
        __syncthreads();

        // lane l consumes chunks {l, l+64, l+128, l+192}: LDS reads lane-sequential
        float hv[4][8];
#pragma unroll
        for (int k = 0; k < 4; ++k) {
            const float4* hp = (const float4*)(h_s + (lane + 64 * k) * 8);
            float4 a = hp[0], b = hp[1];
            hv[k][0] = a.x; hv[k][1] = a.y; hv[k][2] = a.z; hv[k][3] = a.w;
            hv[k][4] = b.x; hv[k][5] = b.y; hv[k][6] = b.z; hv[k][7] = b.w;
        }
        float acc[6];
#pragma unroll
        for (int q = 0; q < 6; ++q) {
            const uint16_t* wrow = wlds + (wave * 6 + q) * 2048;
            float s = 0.0f;
#pragma unroll
            for (int k = 0; k < 4; ++k) {
                uint4 wv = *(const uint4*)(wrow + (lane + 64 * k) * 8);
                s += bflo(wv.x) * hv[k][0] + bfhi(wv.x) * hv[k][1]
                   + bflo(wv.y) * hv[k][2] + bfhi(wv.y) * hv[k][3]
                   + bflo(wv.z) * hv[k][4] + bfhi(wv.z) * hv[k][5]
                   + bflo(wv.w) * hv[k][6] + bfhi(wv.w) * hv[k][7];
            }
            acc[q] = s;
        }
#pragma unroll
        for (int off = 32; off > 0; off >>= 1) {
#pragma unroll
            for (int q = 0; q < 6; ++q)
                acc[q] += __shfl_xor(acc[q], off, 64);
        }

        if (lane == 0) {
            float hn2[2];
#pragma unroll
            for (int jj = 0; jj < 2; ++jj) {
                float4 cr = gc[wave * 6 + jj];
                float4 cz = gc[wave * 6 + 2 + jj];
                float4 cn = gc[wave * 6 + 4 + jj];
                float xr = sv.x * cr.x + sv.y * cr.y + cr.z;
                float xz = sv.x * cz.x + sv.y * cz.y + cz.z;
                float xn = sv.x * cn.x + sv.y * cn.y + cn.z;
                float r = sigmoidf_(xr + acc[jj]     + cr.w);
                float z = sigmoidf_(xz + acc[2 + jj] + cz.w);
                float n = tanhf_(xn + r * (acc[4 + jj] + cn.w));
                int i = g * HC + 2 * wave + jj;
                hn2[jj] = (1.0f - z) * n + z * h_s[i];
            }
            // the two h indices are contiguous: one 8B agent store
            ull pk = (ull)__builtin_bit_cast(uint32_t, hn2[0])
                   | ((ull)__builtin_bit_cast(uint32_t, hn2[1]) << 32);
            int i0 = g * HC + 2 * wave;
            st_agent_u64((ull*)(hbuf + (size_t)((t + 1) & 1) * H + i0), pk);
        }
        wait_vm0();        // wave-wide: commit this wave's h store at coherence point
        __syncthreads();   // all 4 waves' stores committed
        if (tid == 0) st_agent_i32(&stamps[g], t + 1);
    }

    // ---- epilogue: WG 0 computes sigmoid(h_T . fc_w + fc_b) ----
    if (g == 0) {
        while (ld_agent_i32(&stamps[tid]) < T_STEPS) {
            __builtin_amdgcn_s_sleep(1);
        }
        __atomic_signal_fence(__ATOMIC_SEQ_CST);
        const ull* hsrc = (const ull*)(hbuf + (size_t)(T_STEPS & 1) * H) + tid * 4;
        ull d0 = ld_agent_u64(hsrc + 0);
        ull d1 = ld_agent_u64(hsrc + 1);
        ull d2 = ld_agent_u64(hsrc + 2);
        ull d3 = ld_agent_u64(hsrc + 3);
        float hv[8];
        *(ull*)(hv + 0) = d0; *(ull*)(hv + 2) = d1;
        *(ull*)(hv + 4) = d2; *(ull*)(hv + 6) = d3;
        float p = 0.0f;
#pragma unroll
        for (int e = 0; e < 8; ++e)
            p += hv[e] * fc_w[tid * 8 + e];
#pragma unroll
        for (int off = 32; off > 0; off >>= 1)
            p += __shfl_xor(p, off, 64);
        if (lane == 0) red[wave] = p;
        __syncthreads();
        if (tid == 0) {
            float s = red[0] + red[1] + red[2] + red[3];
            out[0] = sigmoidf_(s + fc_b[0]);
        }
    }
}

extern "C" void kernel_launch(void* const* d_in, const int* in_sizes, int n_in,
                              void* d_out, int out_size, void* d_ws, size_t ws_size,
                              hipStream_t stream) {
    const float* samples = (const float*)d_in[0];
    const float* w_ih    = (const float*)d_in[1];
    const float* w_hh    = (const float*)d_in[2];
    const float* b_ih    = (const float*)d_in[3];
    const float* b_hh    = (const float*)d_in[4];
    const float* fc_w    = (const float*)d_in[5];
    const float* fc_b    = (const float*)d_in[6];
    float* out    = (float*)d_out;
    float* hbuf   = (float*)d_ws;                                   // 16 KB
    int*   stamps = (int*)((char*)d_ws + 2 * H * sizeof(float));    // 1 KB

    hipLaunchKernelGGL(init_stamps_kernel, dim3(1), dim3(WGSIZE), 0, stream, stamps);

    hipFuncSetAttribute((const void*)gru_persistent_kernel,
                        hipFuncAttributeMaxDynamicSharedMemorySize, LDS_BYTES);

    void* args[] = {(void*)&samples, (void*)&w_ih, (void*)&w_hh, (void*)&b_ih,
                    (void*)&b_hh, (void*)&fc_w, (void*)&fc_b,
                    (void*)&out, (void*)&hbuf, (void*)&stamps};
    hipError_t rc = hipLaunchCooperativeKernel(
        reinterpret_cast<void*>(gru_persistent_kernel),
        dim3(G), dim3(WGSIZE), args, LDS_BYTES, stream);
    if (rc != hipSuccess) {
        hipLaunchKernelGGL(gru_persistent_kernel, dim3(G), dim3(WGSIZE), LDS_BYTES, stream,
                           samples, w_ih, w_hh, b_ih, b_hh, fc_w, fc_b, out, hbuf, stamps);
    }
}

// Round 3
// 101963.361 us; speedup vs baseline: 3.0455x; 1.3637x over previous
//
#include <hip/hip_runtime.h>
#include <cstdint>
#include <cstddef>

#define H        2048
#define T_STEPS  16384
#define G        256     // workgroups == CUs, 1 WG/CU
#define HC       8       // h indices per WG (H/G)
#define NROW     24      // 3 gates * HC rows of w_hh per WG
#define WGSIZE   256

// LDS layout (bytes)
#define LDS_W_OFF    0                        // bf16 weights: 24 rows * 2048 cols * 2B = 96KB
#define LDS_H_OFF    98304                    // float h_s[2][2048] (parity double-buffer)
#define LDS_GC_OFF   (98304 + 16384)          // float4 gc[24]: (wi0, wi1, b_ih, b_hh)
#define LDS_RED_OFF  (98304 + 16384 + 384)    // float red[8]
#define LDS_BYTES    (98304 + 16384 + 384 + 32)

typedef unsigned long long ull;
typedef unsigned int uv4 __attribute__((ext_vector_type(4)));

__device__ __forceinline__ float sigmoidf_(float x) {
    return 1.0f / (1.0f + __expf(-x));
}
__device__ __forceinline__ float tanhf_(float x) {
    return 1.0f - 2.0f / (__expf(2.0f * x) + 1.0f);
}
// fp32 -> bf16 round-to-nearest-even
__device__ __forceinline__ uint16_t f2bf(float f) {
    uint32_t u = __builtin_bit_cast(uint32_t, f);
    return (uint16_t)((u + 0x7FFFu + ((u >> 16) & 1u)) >> 16);
}
__device__ __forceinline__ float bflo(uint32_t d) { return __builtin_bit_cast(float, d << 16); }
__device__ __forceinline__ float bfhi(uint32_t d) { return __builtin_bit_cast(float, d & 0xFFFF0000u); }

// relaxed agent-scope atomics: bypass non-coherent L2, no fence instructions
__device__ __forceinline__ void st_agent_u64(ull* p, ull v) {
    __hip_atomic_store(p, v, __ATOMIC_RELAXED, __HIP_MEMORY_SCOPE_AGENT);
}

// hline layout: [2 parities][256 lines][8 slots of {f32 h, u32 tag}] = 32KB
__global__ void init_hline_kernel(ull* __restrict__ hl) {
    int i = blockIdx.x * 256 + threadIdx.x;            // 0..4095
    // parity 0: h=0.0f tagged 0 (the t=0 state). parity 1: invalid sentinel.
    ull v = (i < 2048) ? 0ull : 0xFFFFFFFF00000000ull;
    st_agent_u64(hl + i, v);
}

extern "C" __global__ void __launch_bounds__(WGSIZE, 1)
gru_persistent_kernel(const float* __restrict__ samples,
                      const float* __restrict__ w_ih,
                      const float* __restrict__ w_hh,
                      const float* __restrict__ b_ih,
                      const float* __restrict__ b_hh,
                      const float* __restrict__ fc_w,
                      const float* __restrict__ fc_b,
                      float* __restrict__ out,
                      ull*   __restrict__ hline)   // [2][256][8] slots in d_ws
{
    extern __shared__ char smem[];
    uint16_t* wlds = (uint16_t*)(smem + LDS_W_OFF);
    float*    h_sb = (float*)(smem + LDS_H_OFF);     // [2][2048]
    float4*   gc   = (float4*)(smem + LDS_GC_OFF);
    float*    red  = (float*)(smem + LDS_RED_OFF);

    const int g    = blockIdx.x;
    const int tid  = threadIdx.x;
    const int wave = tid >> 6;
    const int lane = tid & 63;

    // ---- one-time: stage this WG's 24 w_hh rows into LDS as bf16 ----
    // Row slot rho = wave_r*6 + gate*2 + jj ; global h index i = g*8 + 2*wave_r + jj
    for (int rho = 0; rho < NROW; ++rho) {
        int w_r  = rho / 6;
        int rem  = rho - 6 * w_r;
        int gate = rem >> 1;
        int jj   = rem & 1;
        int grow = gate * H + g * HC + 2 * w_r + jj;
        const float* src = w_hh + (size_t)grow * H + tid * 8;
        float4 a = *(const float4*)(src);
        float4 b = *(const float4*)(src + 4);
        uint4 p;
        p.x = (uint32_t)f2bf(a.x) | ((uint32_t)f2bf(a.y) << 16);
        p.y = (uint32_t)f2bf(a.z) | ((uint32_t)f2bf(a.w) << 16);
        p.z = (uint32_t)f2bf(b.x) | ((uint32_t)f2bf(b.y) << 16);
        p.w = (uint32_t)f2bf(b.z) | ((uint32_t)f2bf(b.w) << 16);
        *(uint4*)(wlds + rho * 2048 + tid * 8) = p;
    }
    if (tid < NROW) {
        int rho  = tid;
        int w_r  = rho / 6;
        int rem  = rho - 6 * w_r;
        int gate = rem >> 1;
        int jj   = rem & 1;
        int grow = gate * H + g * HC + 2 * w_r + jj;
        gc[rho] = make_float4(w_ih[grow * 2 + 0], w_ih[grow * 2 + 1], b_ih[grow], b_hh[grow]);
    }
    __syncthreads();

    // ---- 16384 sequential steps; ONE barrier per step ----
    for (int t = 0; t < T_STEPS; ++t) {
        float2 sv = *(const float2*)(samples + 2 * (size_t)t);
        const int p = t & 1;
        float* h_s = h_sb + p * H;

        // poll OUR line (64B = WG tid's 8 tagged h values) until all tags==t.
        // The poll IS the data load: 4x16B system-coherent loads, no 2nd gather.
        const ull* lp = hline + ((size_t)p * G + tid) * 8;
        const uint32_t tu = (uint32_t)t;
        uv4 q0, q1, q2, q3;
        for (;;) {
            asm volatile(
                "global_load_dwordx4 %0, %4, off sc0 sc1\n\t"
                "global_load_dwordx4 %1, %4, off offset:16 sc0 sc1\n\t"
                "global_load_dwordx4 %2, %4, off offset:32 sc0 sc1\n\t"
                "global_load_dwordx4 %3, %4, off offset:48 sc0 sc1\n\t"
                "s_waitcnt vmcnt(0)"
                : "=v"(q0), "=v"(q1), "=v"(q2), "=v"(q3)
                : "v"(lp)
                : "memory");
            bool ok = (q0.y == tu) & (q0.w == tu) & (q1.y == tu) & (q1.w == tu)
                    & (q2.y == tu) & (q2.w == tu) & (q3.y == tu) & (q3.w == tu);
            if (ok) break;
            __builtin_amdgcn_s_sleep(1);
        }
        // stage the 8 h values (slots' low dwords) into this parity's LDS buffer
        float4 f0 = make_float4(__builtin_bit_cast(float, q0.x), __builtin_bit_cast(float, q0.z),
                                __builtin_bit_cast(float, q1.x), __builtin_bit_cast(float, q1.z));
        float4 f1 = make_float4(__builtin_bit_cast(float, q2.x), __builtin_bit_cast(float, q2.z),
                                __builtin_bit_cast(float, q3.x), __builtin_bit_cast(float, q3.z));
        *(float4*)(h_s + tid * 8)     = f0;
        *(float4*)(h_s + tid * 8 + 4) = f1;
        __syncthreads();   // the only barrier: h_s[p] complete before compute

        // lane l consumes chunks {l, l+64, l+128, l+192}: LDS reads lane-sequential
        float hv[4][8];
#pragma unroll
        for (int k = 0; k < 4; ++k) {
            const float4* hp = (const float4*)(h_s + (lane + 64 * k) * 8);
            float4 a = hp[0], b = hp[1];
            hv[k][0] = a.x; hv[k][1] = a.y; hv[k][2] = a.z; hv[k][3] = a.w;
            hv[k][4] = b.x; hv[k][5] = b.y; hv[k][6] = b.z; hv[k][7] = b.w;
        }
        float acc[6];
#pragma unroll
        for (int q = 0; q < 6; ++q) {
            const uint16_t* wrow = wlds + (wave * 6 + q) * 2048;
            float s = 0.0f;
#pragma unroll
            for (int k = 0; k < 4; ++k) {
                uint4 wv = *(const uint4*)(wrow + (lane + 64 * k) * 8);
                s += bflo(wv.x) * hv[k][0] + bfhi(wv.x) * hv[k][1]
                   + bflo(wv.y) * hv[k][2] + bfhi(wv.y) * hv[k][3]
                   + bflo(wv.z) * hv[k][4] + bfhi(wv.z) * hv[k][5]
                   + bflo(wv.w) * hv[k][6] + bfhi(wv.w) * hv[k][7];
            }
            acc[q] = s;
        }
#pragma unroll
        for (int off = 32; off > 0; off >>= 1) {
#pragma unroll
            for (int q = 0; q < 6; ++q)
                acc[q] += __shfl_xor(acc[q], off, 64);
        }

        if (lane == 0) {
            float hn2[2];
#pragma unroll
            for (int jj = 0; jj < 2; ++jj) {
                float4 cr = gc[wave * 6 + jj];
                float4 cz = gc[wave * 6 + 2 + jj];
                float4 cn = gc[wave * 6 + 4 + jj];
                float xr = sv.x * cr.x + sv.y * cr.y + cr.z;
                float xz = sv.x * cz.x + sv.y * cz.y + cz.z;
                float xn = sv.x * cn.x + sv.y * cn.y + cn.z;
                float r = sigmoidf_(xr + acc[jj]     + cr.w);
                float z = sigmoidf_(xz + acc[2 + jj] + cz.w);
                float n = tanhf_(xn + r * (acc[4 + jj] + cn.w));
                int i = g * HC + 2 * wave + jj;
                hn2[jj] = (1.0f - z) * n + z * h_s[i];
            }
            // two tagged fire-and-forget stores; tag carries validity, no vmcnt
            uint32_t tagv = (uint32_t)(t + 1);
            ull s0 = (ull)__builtin_bit_cast(uint32_t, hn2[0]) | ((ull)tagv << 32);
            ull s1 = (ull)__builtin_bit_cast(uint32_t, hn2[1]) | ((ull)tagv << 32);
            ull* dst = hline + ((size_t)((t + 1) & 1) * G + g) * 8 + wave * 2;
            st_agent_u64(dst,     s0);
            st_agent_u64(dst + 1, s1);
        }
        // no end-of-step barrier: next step stages into the OTHER LDS parity
    }

    // ---- epilogue: WG 0 computes sigmoid(h_T . fc_w + fc_b) ----
    if (g == 0) {
        const ull* lp = hline + ((size_t)(T_STEPS & 1) * G + tid) * 8;
        const uint32_t tu = (uint32_t)T_STEPS;
        uv4 q0, q1, q2, q3;
        for (;;) {
            asm volatile(
                "global_load_dwordx4 %0, %4, off sc0 sc1\n\t"
                "global_load_dwordx4 %1, %4, off offset:16 sc0 sc1\n\t"
                "global_load_dwordx4 %2, %4, off offset:32 sc0 sc1\n\t"
                "global_load_dwordx4 %3, %4, off offset:48 sc0 sc1\n\t"
                "s_waitcnt vmcnt(0)"
                : "=v"(q0), "=v"(q1), "=v"(q2), "=v"(q3)
                : "v"(lp)
                : "memory");
            bool ok = (q0.y == tu) & (q0.w == tu) & (q1.y == tu) & (q1.w == tu)
                    & (q2.y == tu) & (q2.w == tu) & (q3.y == tu) & (q3.w == tu);
            if (ok) break;
            __builtin_amdgcn_s_sleep(1);
        }
        float hv[8];
        hv[0] = __builtin_bit_cast(float, q0.x); hv[1] = __builtin_bit_cast(float, q0.z);
        hv[2] = __builtin_bit_cast(float, q1.x); hv[3] = __builtin_bit_cast(float, q1.z);
        hv[4] = __builtin_bit_cast(float, q2.x); hv[5] = __builtin_bit_cast(float, q2.z);
        hv[6] = __builtin_bit_cast(float, q3.x); hv[7] = __builtin_bit_cast(float, q3.z);
        float pacc = 0.0f;
#pragma unroll
        for (int e = 0; e < 8; ++e)
            pacc += hv[e] * fc_w[tid * 8 + e];
#pragma unroll
        for (int off = 32; off > 0; off >>= 1)
            pacc += __shfl_xor(pacc, off, 64);
        if (lane == 0) red[wave] = pacc;
        __syncthreads();
        if (tid == 0) {
            float s = red[0] + red[1] + red[2] + red[3];
            out[0] = sigmoidf_(s + fc_b[0]);
        }
    }
}

extern "C" void kernel_launch(void* const* d_in, const int* in_sizes, int n_in,
                              void* d_out, int out_size, void* d_ws, size_t ws_size,
                              hipStream_t stream) {
    const float* samples = (const float*)d_in[0];
    const float* w_ih    = (const float*)d_in[1];
    const float* w_hh    = (const float*)d_in[2];
    const float* b_ih    = (const float*)d_in[3];
    const float* b_hh    = (const float*)d_in[4];
    const float* fc_w    = (const float*)d_in[5];
    const float* fc_b    = (const float*)d_in[6];
    float* out   = (float*)d_out;
    ull*   hline = (ull*)d_ws;    // [2][256][8] tagged slots = 32KB

    // seed parity-0 = h0 (zeros, tag 0); parity-1 = sentinel
    hipLaunchKernelGGL(init_hline_kernel, dim3(16), dim3(256), 0, stream, hline);

    hipFuncSetAttribute((const void*)gru_persistent_kernel,
                        hipFuncAttributeMaxDynamicSharedMemorySize, LDS_BYTES);

    void* args[] = {(void*)&samples, (void*)&w_ih, (void*)&w_hh, (void*)&b_ih,
                    (void*)&b_hh, (void*)&fc_w, (void*)&fc_b,
                    (void*)&out, (void*)&hline};
    hipError_t rc = hipLaunchCooperativeKernel(
        reinterpret_cast<void*>(gru_persistent_kernel),
        dim3(G), dim3(WGSIZE), args, LDS_BYTES, stream);
    if (rc != hipSuccess) {
        hipLaunchKernelGGL(gru_persistent_kernel, dim3(G), dim3(WGSIZE), LDS_BYTES, stream,
                           samples, w_ih, w_hh, b_ih, b_hh, fc_w, fc_b, out, hline);
    }
}

// Round 4
// 77124.127 us; speedup vs baseline: 4.0263x; 1.3221x over previous
//
#include <hip/hip_runtime.h>
#include <cstdint>
#include <cstddef>

#define H        2048
#define T_STEPS  16384
#define G        256     // workgroups == CUs, 1 WG/CU
#define HC       8       // h indices per WG (H/G)
#define NROW     24      // 3 gates * HC rows of w_hh per WG
#define WGSIZE   256

// LDS layout (bytes)
#define LDS_W_OFF    0                        // f16 weights: 24 rows * 2048 cols * 2B = 96KB
#define LDS_H16_OFF  98304                    // uint32 h16[2][1024] packed f16x2 pairs = 8KB
#define LDS_GC_OFF   (98304 + 8192)           // float4 gc[24]: (wi0, wi1, b_ih, b_hh)
#define LDS_RED_OFF  (98304 + 8192 + 384)     // float red[8]
#define LDS_BYTES    (98304 + 8192 + 384 + 32)

typedef unsigned long long ull;
typedef unsigned int uv4 __attribute__((ext_vector_type(4)));
typedef _Float16 half2_ __attribute__((ext_vector_type(2)));

__device__ __forceinline__ float sigmoidf_(float x) {
    return 1.0f / (1.0f + __expf(-x));
}
__device__ __forceinline__ float tanhf_(float x) {
    return 1.0f - 2.0f / (__expf(2.0f * x) + 1.0f);
}
// f32 pair -> packed f16x2 (RNE via default round mode)
__device__ __forceinline__ uint32_t pack_f16x2(float a, float b) {
    _Float16 ha = (_Float16)a, hb = (_Float16)b;
    return (uint32_t)__builtin_bit_cast(uint16_t, ha)
         | ((uint32_t)__builtin_bit_cast(uint16_t, hb) << 16);
}
__device__ __forceinline__ float f16lo(uint32_t d) {
    return (float)__builtin_bit_cast(_Float16, (uint16_t)(d & 0xFFFFu));
}
__device__ __forceinline__ float f16hi(uint32_t d) {
    return (float)__builtin_bit_cast(_Float16, (uint16_t)(d >> 16));
}
// packed f16 dot2 with f32 accumulate: v_dot2_f32_f16
__device__ __forceinline__ float dot2f(uint32_t w, uint32_t h, float acc) {
#if __has_builtin(__builtin_amdgcn_fdot2)
    return __builtin_amdgcn_fdot2(__builtin_bit_cast(half2_, w),
                                  __builtin_bit_cast(half2_, h), acc, false);
#else
    return acc + f16lo(w) * f16lo(h) + f16hi(w) * f16hi(h);
#endif
}

// relaxed agent-scope atomics: bypass non-coherent L2, no fence instructions
__device__ __forceinline__ void st_agent_u64(ull* p, ull v) {
    __hip_atomic_store(p, v, __ATOMIC_RELAXED, __HIP_MEMORY_SCOPE_AGENT);
}

// hline layout: [2 parities][1024 slots of {f16x2 pair, u32 tag}] = 16KB
__global__ void init_hline_kernel(ull* __restrict__ hl) {
    int i = blockIdx.x * 256 + threadIdx.x;            // 0..2047
    // parity 0: h=(0,0) tagged 0 (the t=0 state). parity 1: invalid sentinel.
    ull v = (i < 1024) ? 0ull : 0xFFFFFFFF00000000ull;
    st_agent_u64(hl + i, v);
}

extern "C" __global__ void __launch_bounds__(WGSIZE, 1)
gru_persistent_kernel(const float* __restrict__ samples,
                      const float* __restrict__ w_ih,
                      const float* __restrict__ w_hh,
                      const float* __restrict__ b_ih,
                      const float* __restrict__ b_hh,
                      const float* __restrict__ fc_w,
                      const float* __restrict__ fc_b,
                      float* __restrict__ out,
                      ull*   __restrict__ hline)   // [2][1024] tagged f16x2 slots
{
    extern __shared__ char smem[];
    uint32_t* wlds = (uint32_t*)(smem + LDS_W_OFF);    // f16x2 dwords, row stride 1024
    uint32_t* h16s = (uint32_t*)(smem + LDS_H16_OFF);  // [2][1024] f16x2 pairs
    float4*   gc   = (float4*)(smem + LDS_GC_OFF);
    float*    red  = (float*)(smem + LDS_RED_OFF);

    const int g    = blockIdx.x;
    const int tid  = threadIdx.x;
    const int wave = tid >> 6;
    const int lane = tid & 63;

    // ---- one-time: stage this WG's 24 w_hh rows into LDS as f16 ----
    // Row slot rho = wave_r*6 + gate*2 + jj ; global h index i = g*8 + 2*wave_r + jj
    for (int rho = 0; rho < NROW; ++rho) {
        int w_r  = rho / 6;
        int rem  = rho - 6 * w_r;
        int gate = rem >> 1;
        int jj   = rem & 1;
        int grow = gate * H + g * HC + 2 * w_r + jj;
        const float* src = w_hh + (size_t)grow * H + tid * 8;
        float4 a = *(const float4*)(src);
        float4 b = *(const float4*)(src + 4);
        uint4 p;
        p.x = pack_f16x2(a.x, a.y);
        p.y = pack_f16x2(a.z, a.w);
        p.z = pack_f16x2(b.x, b.y);
        p.w = pack_f16x2(b.z, b.w);
        *(uint4*)(wlds + rho * 1024 + tid * 4) = p;
    }
    if (tid < NROW) {
        int rho  = tid;
        int w_r  = rho / 6;
        int rem  = rho - 6 * w_r;
        int gate = rem >> 1;
        int jj   = rem & 1;
        int grow = gate * H + g * HC + 2 * w_r + jj;
        gc[rho] = make_float4(w_ih[grow * 2 + 0], w_ih[grow * 2 + 1], b_ih[grow], b_hh[grow]);
    }
    __syncthreads();

    // this wave's two owned h values, kept in f32 registers (lane 0 only uses them)
    float hloc0 = 0.0f, hloc1 = 0.0f;

    // ---- 16384 sequential steps; ONE barrier per step ----
    for (int t = 0; t < T_STEPS; ++t) {
        float2 sv = *(const float2*)(samples + 2 * (size_t)t);
        const int p = t & 1;

        // poll WG tid's 4 slots (32B: 8 h as f16x2 + 4 tags) until tags==t.
        // Poll IS the data load: 2x16B system-coherent loads.
        const ull* lp = hline + (size_t)p * 1024 + tid * 4;
        const uint32_t tu = (uint32_t)t;
        uv4 q0, q1;
        for (;;) {
            asm volatile(
                "global_load_dwordx4 %0, %2, off sc0 sc1\n\t"
                "global_load_dwordx4 %1, %2, off offset:16 sc0 sc1\n\t"
                "s_waitcnt vmcnt(0)"
                : "=v"(q0), "=v"(q1)
                : "v"(lp)
                : "memory");
            if ((q0.y == tu) & (q0.w == tu) & (q1.y == tu) & (q1.w == tu)) break;
            __builtin_amdgcn_s_sleep(2);   // backoff: cut fabric pressure
        }
        // stage the 4 f16x2 pairs into this parity's LDS buffer (one b128 write)
        uint4 hw;
        hw.x = q0.x; hw.y = q0.z; hw.z = q1.x; hw.w = q1.z;
        *(uint4*)(h16s + p * 1024 + tid * 4) = hw;
        __syncthreads();   // the only barrier: h16s[p] complete before compute

        // lane l consumes chunks {l, l+64, l+128, l+192}; 16B per chunk (8 f16)
        uint4 hq[4];
#pragma unroll
        for (int k = 0; k < 4; ++k)
            hq[k] = *(const uint4*)(h16s + p * 1024 + (lane + 64 * k) * 4);

        float acc[6];
#pragma unroll
        for (int q = 0; q < 6; ++q) {
            const uint32_t* wrow = wlds + (wave * 6 + q) * 1024;
            float s = 0.0f;
#pragma unroll
            for (int k = 0; k < 4; ++k) {
                uint4 wv = *(const uint4*)(wrow + (lane + 64 * k) * 4);
                s = dot2f(wv.x, hq[k].x, s);
                s = dot2f(wv.y, hq[k].y, s);
                s = dot2f(wv.z, hq[k].z, s);
                s = dot2f(wv.w, hq[k].w, s);
            }
            acc[q] = s;
        }
#pragma unroll
        for (int off = 32; off > 0; off >>= 1) {
#pragma unroll
            for (int q = 0; q < 6; ++q)
                acc[q] += __shfl_xor(acc[q], off, 64);
        }

        if (lane == 0) {
            float hn2[2];
            float hold[2] = {hloc0, hloc1};
#pragma unroll
            for (int jj = 0; jj < 2; ++jj) {
                float4 cr = gc[wave * 6 + jj];
                float4 cz = gc[wave * 6 + 2 + jj];
                float4 cn = gc[wave * 6 + 4 + jj];
                float xr = sv.x * cr.x + sv.y * cr.y + cr.z;
                float xz = sv.x * cz.x + sv.y * cz.y + cz.z;
                float xn = sv.x * cn.x + sv.y * cn.y + cn.z;
                float r = sigmoidf_(xr + acc[jj]     + cr.w);
                float z = sigmoidf_(xz + acc[2 + jj] + cz.w);
                float n = tanhf_(xn + r * (acc[4 + jj] + cn.w));
                hn2[jj] = (1.0f - z) * n + z * hold[jj];
            }
            hloc0 = hn2[0];
            hloc1 = hn2[1];
            // one tagged fire-and-forget 8B store per wave
            ull s0 = (ull)pack_f16x2(hn2[0], hn2[1]) | ((ull)(uint32_t)(t + 1) << 32);
            st_agent_u64(hline + (size_t)((t + 1) & 1) * 1024 + g * 4 + wave, s0);
        }
        // no end-of-step barrier: next step stages into the OTHER LDS parity
    }

    // ---- epilogue: WG 0 computes sigmoid(h_T . fc_w + fc_b) ----
    if (g == 0) {
        const ull* lp = hline + (size_t)(T_STEPS & 1) * 1024 + tid * 4;
        const uint32_t tu = (uint32_t)T_STEPS;
        uv4 q0, q1;
        for (;;) {
            asm volatile(
                "global_load_dwordx4 %0, %2, off sc0 sc1\n\t"
                "global_load_dwordx4 %1, %2, off offset:16 sc0 sc1\n\t"
                "s_waitcnt vmcnt(0)"
                : "=v"(q0), "=v"(q1)
                : "v"(lp)
                : "memory");
            if ((q0.y == tu) & (q0.w == tu) & (q1.y == tu) & (q1.w == tu)) break;
            __builtin_amdgcn_s_sleep(2);
        }
        float hv[8];
        hv[0] = f16lo(q0.x); hv[1] = f16hi(q0.x);
        hv[2] = f16lo(q0.z); hv[3] = f16hi(q0.z);
        hv[4] = f16lo(q1.x); hv[5] = f16hi(q1.x);
        hv[6] = f16lo(q1.z); hv[7] = f16hi(q1.z);
        float pacc = 0.0f;
#pragma unroll
        for (int e = 0; e < 8; ++e)
            pacc += hv[e] * fc_w[tid * 8 + e];
#pragma unroll
        for (int off = 32; off > 0; off >>= 1)
            pacc += __shfl_xor(pacc, off, 64);
        if (lane == 0) red[wave] = pacc;
        __syncthreads();
        if (tid == 0) {
            float s = red[0] + red[1] + red[2] + red[3];
            out[0] = sigmoidf_(s + fc_b[0]);
        }
    }
}

extern "C" void kernel_launch(void* const* d_in, const int* in_sizes, int n_in,
                              void* d_out, int out_size, void* d_ws, size_t ws_size,
                              hipStream_t stream) {
    const float* samples = (const float*)d_in[0];
    const float* w_ih    = (const float*)d_in[1];
    const float* w_hh    = (const float*)d_in[2];
    const float* b_ih    = (const float*)d_in[3];
    const float* b_hh    = (const float*)d_in[4];
    const float* fc_w    = (const float*)d_in[5];
    const float* fc_b    = (const float*)d_in[6];
    float* out   = (float*)d_out;
    ull*   hline = (ull*)d_ws;    // [2][1024] tagged f16x2 slots = 16KB

    // seed parity-0 = h0 (zeros, tag 0); parity-1 = sentinel
    hipLaunchKernelGGL(init_hline_kernel, dim3(8), dim3(256), 0, stream, hline);

    hipFuncSetAttribute((const void*)gru_persistent_kernel,
                        hipFuncAttributeMaxDynamicSharedMemorySize, LDS_BYTES);

    void* args[] = {(void*)&samples, (void*)&w_ih, (void*)&w_hh, (void*)&b_ih,
                    (void*)&b_hh, (void*)&fc_w, (void*)&fc_b,
                    (void*)&out, (void*)&hline};
    hipError_t rc = hipLaunchCooperativeKernel(
        reinterpret_cast<void*>(gru_persistent_kernel),
        dim3(G), dim3(WGSIZE), args, LDS_BYTES, stream);
    if (rc != hipSuccess) {
        hipLaunchKernelGGL(gru_persistent_kernel, dim3(G), dim3(WGSIZE), LDS_BYTES, stream,
                           samples, w_ih, w_hh, b_ih, b_hh, fc_w, fc_b, out, hline);
    }
}